// Round 8
// baseline (41.767 us; speedup 1.0000x reference)
//
#include <hip/hip_runtime.h>
#include <math.h>

#define DT 0.2f
#define LEN_HIST 16
#define TPB 256

__global__ __launch_bounds__(TPB) void kalman_v3(
    const float* __restrict__ hist,
    const float* __restrict__ vsx_p, const float* __restrict__ vsy_p,
    const float* __restrict__ asx_p, const float* __restrict__ asy_p,
    const float* __restrict__ GR_p,  const float* __restrict__ coefG_p,
    float* __restrict__ out, int B, int len_pred, int fastOK)
{
    __shared__ float sX[4][TPB];   // filtered state, SoA

    const int tid  = threadIdx.x;
    const int base = blockIdx.x * TPB;
    const int b    = base + tid;
    const bool vOK = b < B;
    const int ib   = vOK ? b : (B - 1);

    // ---- constants / noise (per thread, as in r1) ----
    const float Gv0 = DT * DT * 0.5f, Gv1 = DT, Gv2 = DT * DT * 0.5f, Gv3 = DT;
    float ax2 = asx_p[0] * asx_p[0];
    float ay2 = asy_p[0] * asy_p[0];
    float g[4];
    g[0] = Gv0 * tanhf(coefG_p[0]);
    g[1] = Gv1 * tanhf(coefG_p[1]);
    g[2] = Gv2 * tanhf(coefG_p[2]);
    g[3] = Gv3 * tanhf(coefG_p[3]);
    float Q[4][4];
    #pragma unroll
    for (int i = 0; i < 4; ++i)
        #pragma unroll
        for (int j = 0; j < 4; ++j) {
            float s = (i < 2) ? ((j < 2) ? ax2 : 1.0f)
                              : ((j < 2) ? 1.0f : ay2);
            Q[i][j] = g[i] * g[j] * s;
        }
    float GR0 = GR_p[0], GR1 = GR_p[1];
    float R00 = GR0 * GR0, R01 = GR0 * GR1, R10 = GR1 * GR0, R11 = GR1 * GR1;

    // ---- measurements ----
    float2 z[LEN_HIST];
    #pragma unroll
    for (int t = 0; t < LEN_HIST; ++t)
        z[t] = *reinterpret_cast<const float2*>(hist + ((size_t)t * B + ib) * 2);

    // ---- per-thread filter with full Riccati (r1, proven) ----
    float X0 = z[0].x, X1 = (z[1].x - z[0].x) / DT;
    float X2 = z[0].y, X3 = (z[1].y - z[0].y) / DT;
    float P[4][4] = {};
    P[0][0] = R00; P[1][1] = vsx_p[0] * vsx_p[0];
    P[2][2] = R11; P[3][3] = vsy_p[0] * vsy_p[0];

    #pragma unroll
    for (int t = 1; t < LEN_HIST; ++t) {
        float T[4][4];
        #pragma unroll
        for (int j = 0; j < 4; ++j) {
            T[0][j] = P[0][j] + DT * P[1][j];
            T[1][j] = P[1][j];
            T[2][j] = P[2][j] + DT * P[3][j];
            T[3][j] = P[3][j];
        }
        #pragma unroll
        for (int i = 0; i < 4; ++i) {
            P[i][0] = T[i][0] + DT * T[i][1] + Q[i][0];
            P[i][1] = T[i][1]                + Q[i][1];
            P[i][2] = T[i][2] + DT * T[i][3] + Q[i][2];
            P[i][3] = T[i][3]                + Q[i][3];
        }
        float y0 = z[t].x - X0 - DT * X1;
        float y1 = z[t].y - X2 - DT * X3;
        X0 += DT * X1; X2 += DT * X3;
        float S00 = P[0][0] + R00, S01 = P[0][2] + R01;
        float S10 = P[2][0] + R10, S11 = P[2][2] + R11;
        float inv = 1.0f / (S00 * S11 - S01 * S10);
        float Si00 =  S11 * inv, Si01 = -S01 * inv;
        float Si10 = -S10 * inv, Si11 =  S00 * inv;
        float K[4][2];
        #pragma unroll
        for (int i = 0; i < 4; ++i) {
            K[i][0] = P[i][0] * Si00 + P[i][2] * Si10;
            K[i][1] = P[i][0] * Si01 + P[i][2] * Si11;
        }
        X0 += K[0][0] * y0 + K[0][1] * y1;
        X1 += K[1][0] * y0 + K[1][1] * y1;
        X2 += K[2][0] * y0 + K[2][1] * y1;
        X3 += K[3][0] * y0 + K[3][1] * y1;
        float U[4][4];
        #pragma unroll
        for (int i = 0; i < 4; ++i)
            #pragma unroll
            for (int j = 0; j < 4; ++j)
                U[i][j] = P[i][j] - K[i][0] * P[0][j] - K[i][1] * P[2][j];
        float w_[4];
        #pragma unroll
        for (int i = 0; i < 4; ++i)
            w_[i] = K[i][0] * GR0 + K[i][1] * GR1;
        #pragma unroll
        for (int i = 0; i < 4; ++i)
            #pragma unroll
            for (int j = 0; j < 4; ++j)
                P[i][j] = U[i][j] - U[i][0] * K[j][0] - U[i][2] * K[j][1] + w_[i] * w_[j];
    }

    // ---- publish X to LDS (once), single barrier ----
    sX[0][tid] = X0; sX[1][tid] = X1; sX[2][tid] = X2; sX[3][tid] = X3;
    __syncthreads();

    const bool blockFast = fastOK && (base + TPB <= B);

    if (blockFast) {
        // fixed emission geometry for this thread
        const int lane = tid & 63, w = tid >> 6;
        const int q1 = 80 * w + lane;               // float4 index in block chunk
        const int f1 = 4 * q1, tA1 = f1 / 5, c1 = f1 % 5;
        const int tB1 = (tA1 + 1 < TPB) ? tA1 + 1 : TPB - 1;
        const bool has2 = lane < 16;
        const int q2 = q1 + 64;
        const int f2 = 4 * q2, tA2 = f2 / 5, c2 = f2 % 5;
        const int tB2 = (tA2 + 1 < TPB) ? tA2 + 1 : TPB - 1;

        const float a0 = sX[0][tA1], a1 = sX[1][tA1], a2 = sX[2][tA1], a3 = sX[3][tA1];
        const float d0 = sX[0][tB1], d1 = sX[1][tB1], d2 = sX[2][tB1], d3 = sX[3][tB1];
        float e0 = 0, e1 = 0, e2 = 0, e3 = 0, h0 = 0, h1 = 0, h2 = 0, h3 = 0;
        if (has2) {
            e0 = sX[0][tA2]; e1 = sX[1][tA2]; e2 = sX[2][tA2]; e3 = sX[3][tA2];
            h0 = sX[0][tB2]; h1 = sX[1][tB2]; h2 = sX[2][tB2]; h3 = sX[3][tB2];
        }

        float4* __restrict__ out4 = reinterpret_cast<float4*>(out);
        const size_t blk4 = ((size_t)base * 5) >> 2;
        const size_t lst4 = ((size_t)B * 5) >> 2;

        for (int l = 0; l < len_pred; ++l) {
            // shared-value P recursion step -> sx, sy, rho
            float T[4][4];
            #pragma unroll
            for (int j = 0; j < 4; ++j) {
                T[0][j] = P[0][j] + DT * P[1][j];
                T[1][j] = P[1][j];
                T[2][j] = P[2][j] + DT * P[3][j];
                T[3][j] = P[3][j];
            }
            #pragma unroll
            for (int i = 0; i < 4; ++i) {
                P[i][0] = T[i][0] + DT * T[i][1] + Q[i][0];
                P[i][1] = T[i][1]                + Q[i][1];
                P[i][2] = T[i][2] + DT * T[i][3] + Q[i][2];
                P[i][3] = T[i][3]                + Q[i][3];
            }
            const float sx = sqrtf(P[0][0]);
            const float sy = sqrtf(P[2][2]);
            const float rho = (P[0][2] + P[2][0]) / (2.0f * sx * sy);
            const float tl = (float)(l + 1) * DT;

            const float mxA = fmaf(tl, a1, a0), myA = fmaf(tl, a3, a2);
            const float mxB = fmaf(tl, d1, d0), myB = fmaf(tl, d3, d2);

            float4 v;
            {
                const int cc0 = c1;
                v.x = (cc0 == 0) ? mxA : (cc0 == 1) ? myA : (cc0 == 2) ? sx :
                      (cc0 == 3) ? sy  : (cc0 == 4) ? rho : sx;
                const int cc1 = c1 + 1;
                v.y = (cc1 == 1) ? myA : (cc1 == 2) ? sx : (cc1 == 3) ? sy :
                      (cc1 == 4) ? rho : (cc1 == 5) ? mxB : sx;
                const int cc2 = c1 + 2;
                v.z = (cc2 == 2) ? sx : (cc2 == 3) ? sy : (cc2 == 4) ? rho :
                      (cc2 == 5) ? mxB : (cc2 == 6) ? myB : sx;
                const int cc3 = c1 + 3;
                v.w = (cc3 == 3) ? sy : (cc3 == 4) ? rho : (cc3 == 5) ? mxB :
                      (cc3 == 6) ? myB : sx;   // cc3==7 -> next track col2 = sx
            }
            out4[l * lst4 + blk4 + q1] = v;

            if (has2) {
                const float mxE = fmaf(tl, e1, e0), myE = fmaf(tl, e3, e2);
                const float mxH = fmaf(tl, h1, h0), myH = fmaf(tl, h3, h2);
                float4 u;
                const int cc0 = c2;
                u.x = (cc0 == 0) ? mxE : (cc0 == 1) ? myE : (cc0 == 2) ? sx :
                      (cc0 == 3) ? sy  : (cc0 == 4) ? rho : sx;
                const int cc1 = c2 + 1;
                u.y = (cc1 == 1) ? myE : (cc1 == 2) ? sx : (cc1 == 3) ? sy :
                      (cc1 == 4) ? rho : (cc1 == 5) ? mxH : sx;
                const int cc2_ = c2 + 2;
                u.z = (cc2_ == 2) ? sx : (cc2_ == 3) ? sy : (cc2_ == 4) ? rho :
                      (cc2_ == 5) ? mxH : (cc2_ == 6) ? myH : sx;
                const int cc3 = c2 + 3;
                u.w = (cc3 == 3) ? sy : (cc3 == 4) ? rho : (cc3 == 5) ? mxH :
                      (cc3 == 6) ? myH : sx;
                out4[l * lst4 + blk4 + q2] = u;
            }
        }
    } else {
        // proven r1 scalar path (partial last block or alignment fallback)
        for (int l = 0; l < len_pred; ++l) {
            float T[4][4];
            #pragma unroll
            for (int j = 0; j < 4; ++j) {
                T[0][j] = P[0][j] + DT * P[1][j];
                T[1][j] = P[1][j];
                T[2][j] = P[2][j] + DT * P[3][j];
                T[3][j] = P[3][j];
            }
            #pragma unroll
            for (int i = 0; i < 4; ++i) {
                P[i][0] = T[i][0] + DT * T[i][1] + Q[i][0];
                P[i][1] = T[i][1]                + Q[i][1];
                P[i][2] = T[i][2] + DT * T[i][3] + Q[i][2];
                P[i][3] = T[i][3]                + Q[i][3];
            }
            X0 += DT * X1; X2 += DT * X3;
            if (vOK) {
                float sx = sqrtf(P[0][0]);
                float sy = sqrtf(P[2][2]);
                float rho = (P[0][2] + P[2][0]) / (2.0f * sx * sy);
                float* o = out + ((size_t)l * B + b) * 5;
                o[0] = X0; o[1] = X2; o[2] = sx; o[3] = sy; o[4] = rho;
            }
        }
    }
}

extern "C" void kernel_launch(void* const* d_in, const int* in_sizes, int n_in,
                              void* d_out, int out_size, void* d_ws, size_t ws_size,
                              hipStream_t stream) {
    const float* hist  = (const float*)d_in[0];
    const float* vsx   = (const float*)d_in[1];
    const float* vsy   = (const float*)d_in[2];
    const float* asx   = (const float*)d_in[3];
    const float* asy   = (const float*)d_in[4];
    const float* GR    = (const float*)d_in[5];
    const float* coefG = (const float*)d_in[6];
    float* out = (float*)d_out;

    int B = in_sizes[0] / (LEN_HIST * 2);
    int len_pred = out_size / (B * 5);

    int fastOK = (((size_t)B * 5) % 4 == 0) ? 1 : 0;

    int grid = (B + TPB - 1) / TPB;
    kalman_v3<<<grid, TPB, 0, stream>>>(hist, vsx, vsy, asx, asy, GR, coefG,
                                        out, B, len_pred, fastOK);
}

// Round 9
// 23.659 us; speedup vs baseline: 1.7654x; 1.7654x over previous
//
#include <hip/hip_runtime.h>
#include <math.h>

#define DT 0.2f
#define LEN_HIST 16
#define TPB 256

// v4: r1 skeleton (single dispatch, no LDS, no barriers, per-thread filter,
// scalar stores) + symmetric-triangle covariance (10 elems) + simple-form
// measurement update. ~2x fewer VALU insts per thread than r1.
__global__ __launch_bounds__(TPB) void kalman_v4(
    const float* __restrict__ hist,
    const float* __restrict__ vsx_p, const float* __restrict__ vsy_p,
    const float* __restrict__ asx_p, const float* __restrict__ asy_p,
    const float* __restrict__ GR_p,  const float* __restrict__ coefG_p,
    float* __restrict__ out, int B, int len_pred)
{
    const int b = blockIdx.x * TPB + threadIdx.x;
    if (b >= B) return;

    // ---- measurements first: 16 coalesced float2 loads, all in flight ----
    float2 z[LEN_HIST];
    #pragma unroll
    for (int t = 0; t < LEN_HIST; ++t)
        z[t] = *reinterpret_cast<const float2*>(hist + ((size_t)t * B + b) * 2);

    // ---- constants: Q (triangle), R ----
    const float d = DT;
    const float Gv0 = DT * DT * 0.5f, Gv1 = DT, Gv2 = DT * DT * 0.5f, Gv3 = DT;
    const float ax2 = asx_p[0] * asx_p[0];
    const float ay2 = asy_p[0] * asy_p[0];
    const float g0 = Gv0 * tanhf(coefG_p[0]);
    const float g1 = Gv1 * tanhf(coefG_p[1]);
    const float g2 = Gv2 * tanhf(coefG_p[2]);
    const float g3 = Gv3 * tanhf(coefG_p[3]);
    // scale_ij = ax2 (i,j<2), ay2 (i,j>=2), 1 (cross)
    const float Q00 = g0 * g0 * ax2, Q01 = g0 * g1 * ax2;
    const float Q02 = g0 * g2,       Q03 = g0 * g3;
    const float Q11 = g1 * g1 * ax2, Q12 = g1 * g2, Q13 = g1 * g3;
    const float Q22 = g2 * g2 * ay2, Q23 = g2 * g3 * ay2, Q33 = g3 * g3 * ay2;
    const float GR0 = GR_p[0], GR1 = GR_p[1];
    const float R00 = GR0 * GR0, R01 = GR0 * GR1, R11 = GR1 * GR1;

    // ---- init ----
    float X0 = z[0].x, X1 = (z[1].x - z[0].x) / DT;
    float X2 = z[0].y, X3 = (z[1].y - z[0].y) / DT;
    float P00 = R00,                P01 = 0.f, P02 = 0.f, P03 = 0.f;
    float P11 = vsx_p[0] * vsx_p[0], P12 = 0.f, P13 = 0.f;
    float P22 = R11,                P23 = 0.f;
    float P33 = vsy_p[0] * vsy_p[0];

    // ---- filter: 15 updates, symmetric triangle, simple-form ----
    #pragma unroll
    for (int t = 1; t < LEN_HIST; ++t) {
        // predict: nP = F P F^T + Q (triangle)
        const float n00 = P00 + d * (P01 + P01 + d * P11) + Q00;
        const float n01 = P01 + d * P11 + Q01;
        const float n02 = P02 + d * (P03 + P12 + d * P13) + Q02;
        const float n03 = P03 + d * P13 + Q03;
        const float n11 = P11 + Q11;
        const float n12 = P12 + d * P13 + Q12;
        const float n13 = P13 + Q13;
        const float n22 = P22 + d * (P23 + P23 + d * P33) + Q22;
        const float n23 = P23 + d * P33 + Q23;
        const float n33 = P33 + Q33;

        // state predict + innovation
        X0 += d * X1; X2 += d * X3;
        const float y0 = z[t].x - X0;
        const float y1 = z[t].y - X2;

        // S = H nP H^T + R (2x2 symmetric), inverse
        const float S00 = n00 + R00, S01 = n02 + R01, S11 = n22 + R11;
        const float inv = 1.0f / (S00 * S11 - S01 * S01);
        const float Si00 = S11 * inv, Si01 = -S01 * inv, Si11 = S00 * inv;

        // K = nP[:, (0,2)] * Sinv
        const float K00 = n00 * Si00 + n02 * Si01, K01 = n00 * Si01 + n02 * Si11;
        const float K10 = n01 * Si00 + n12 * Si01, K11 = n01 * Si01 + n12 * Si11;
        const float K20 = n02 * Si00 + n22 * Si01, K21 = n02 * Si01 + n22 * Si11;
        const float K30 = n03 * Si00 + n23 * Si01, K31 = n03 * Si01 + n23 * Si11;

        X0 += K00 * y0 + K01 * y1;
        X1 += K10 * y0 + K11 * y1;
        X2 += K20 * y0 + K21 * y1;
        X3 += K30 * y0 + K31 * y1;

        // P = (I - K H) nP, symmetric triangle
        // nP row0 = (n00,n01,n02,n03); row2 = (n02,n12,n22,n23)
        P00 = n00 - K00 * n00 - K01 * n02;
        P01 = n01 - K00 * n01 - K01 * n12;
        P02 = n02 - K00 * n02 - K01 * n22;
        P03 = n03 - K00 * n03 - K01 * n23;
        P11 = n11 - K10 * n01 - K11 * n12;
        P12 = n12 - K10 * n02 - K11 * n22;
        P13 = n13 - K10 * n03 - K11 * n23;
        P22 = n22 - K20 * n02 - K21 * n22;
        P23 = n23 - K20 * n03 - K21 * n23;
        P33 = n33 - K30 * n03 - K31 * n23;
    }

    // ---- prediction: triangle recursion, scalar stores (r1 pattern) ----
    float* o = out + (size_t)b * 5;
    const size_t ostride = (size_t)B * 5;
    for (int l = 0; l < len_pred; ++l) {
        const float n00 = P00 + d * (P01 + P01 + d * P11) + Q00;
        const float n01 = P01 + d * P11 + Q01;
        const float n02 = P02 + d * (P03 + P12 + d * P13) + Q02;
        const float n03 = P03 + d * P13 + Q03;
        const float n11 = P11 + Q11;
        const float n12 = P12 + d * P13 + Q12;
        const float n13 = P13 + Q13;
        const float n22 = P22 + d * (P23 + P23 + d * P33) + Q22;
        const float n23 = P23 + d * P33 + Q23;
        const float n33 = P33 + Q33;
        P00 = n00; P01 = n01; P02 = n02; P03 = n03;
        P11 = n11; P12 = n12; P13 = n13;
        P22 = n22; P23 = n23; P33 = n33;

        X0 += d * X1; X2 += d * X3;

        const float sx = sqrtf(P00);
        const float sy = sqrtf(P22);
        const float rho = P02 / (sx * sy);   // == (P02+P20)/(2 sx sy), symmetric

        o[0] = X0; o[1] = X2; o[2] = sx; o[3] = sy; o[4] = rho;
        o += ostride;
    }
}

extern "C" void kernel_launch(void* const* d_in, const int* in_sizes, int n_in,
                              void* d_out, int out_size, void* d_ws, size_t ws_size,
                              hipStream_t stream) {
    const float* hist  = (const float*)d_in[0];
    const float* vsx   = (const float*)d_in[1];
    const float* vsy   = (const float*)d_in[2];
    const float* asx   = (const float*)d_in[3];
    const float* asy   = (const float*)d_in[4];
    const float* GR    = (const float*)d_in[5];
    const float* coefG = (const float*)d_in[6];
    float* out = (float*)d_out;

    int B = in_sizes[0] / (LEN_HIST * 2);
    int len_pred = out_size / (B * 5);

    int grid = (B + TPB - 1) / TPB;
    kalman_v4<<<grid, TPB, 0, stream>>>(hist, vsx, vsy, asx, asy, GR, coefG,
                                        out, B, len_pred);
}